// Round 7
// baseline (535.617 us; speedup 1.0000x reference)
//
#include <hip/hip_runtime.h>

// ---------------------------------------------------------------------------
// GCN forward. Evidence-driven design (R4-R22):
//  - R21 DIAGNOSTIC RESULT: agg_o4 rep=4 -> 104us, FETCH 313MB (78MB/pass =
//    compulsory floor for random cols over 8 private L2s), 3.2TB/s fabric,
//    VALUBusy 27%, 0 bank conflicts. Natural agg_o4 ~ 37us (22 gather + 15
//    overhead); aggs total ~95us of 333. Agg is at its traffic floor.
//  - ~240us of the pipeline is NOT aggs. Models say GEMMs ~15, precompute
//    ~50, L3 ~15 -> mismatch. R22 = second measurement round: rep the other
//    repeatable kernels (gemm x3: staging + K-loop accumulate-and-scale;
//    fill: idempotent rewrite; gemv + agg_small: accumulate-and-scale).
//    Opaque-zero (asm "+v") index perturbation defeats LICM/CSE (rule #17).
//    Aggs back to rep=1 (already measured).
//  - Numerics: accumulate-and-scale at rep=4 perturbs by ~1e-7 rel (validated
//    in R21: absmax bit-identical 0.0009765625).
//  - Production structure unchanged: MFMA GEMMs (W pre-swizzled in LDS),
//    single-pass aggs (256B bf16 rows, TPN=16 uint4, 8-deep pipeline,
//    cached epack, NT output stores), packed-atomic CSR precompute,
//    degree-sorted perm.
// ---------------------------------------------------------------------------

#define BT 256
#define SCAN_B 256

typedef float nfloat4 __attribute__((ext_vector_type(4)));
typedef float nfloat2 __attribute__((ext_vector_type(2)));
typedef unsigned int nuint4 __attribute__((ext_vector_type(4)));
typedef __attribute__((ext_vector_type(8))) short shortx8;   // 8 bf16 (A/B frag)
typedef __attribute__((ext_vector_type(4))) float floatx4;   // C/D frag

__device__ inline float bf_lo(unsigned int v) { return __uint_as_float(v << 16); }
__device__ inline float bf_hi(unsigned int v) { return __uint_as_float(v & 0xFFFF0000u); }
__device__ inline unsigned short f2bf(float f) {  // round-to-nearest-even
    unsigned int u = __float_as_uint(f);
    unsigned int r = u + 0x7FFFu + ((u >> 16) & 1u);
    return (unsigned short)(r >> 16);
}

// opaque zero: runtime 0 the compiler cannot fold -> defeats LICM/CSE of
// repeated diagnostic passes (guide rule #17/#18).
__device__ inline int opaque_zero() {
    int zr = 0;
    asm volatile("" : "+v"(zr));
    return zr;
}

// ---------------- precompute ----------------
__global__ void zero_kernel(unsigned int* buf, int n) {
    int i = blockIdx.x * blockDim.x + threadIdx.x;
    if (i < n) buf[i] = 0u;
}

__global__ void hist_kernel(const int* __restrict__ row, const float* __restrict__ w,
                            unsigned int* cw, int* __restrict__ rank, int e) {
    int i = blockIdx.x * blockDim.x + threadIdx.x;
    if (i >= e) return;
    unsigned int wq = (unsigned int)(w[i] * 65536.0f + 0.5f);
    unsigned int old = atomicAdd(&cw[row[i]], (1u << 24) | wq);
    rank[i] = (int)(old >> 24);
}

// FUSED: block-scan of counts + dis + hierarchical degree histogram
__global__ __launch_bounds__(SCAN_B) void nodeprep_kernel(const unsigned int* __restrict__ cw,
                                                          int* rowptr, int* bsums, float* dis,
                                                          int* dbin, int* __restrict__ nrank,
                                                          int n) {
    __shared__ int s[SCAN_B];
    __shared__ int lbin[256];
    __shared__ int lbase[256];
    const int t = threadIdx.x;
    const int i = blockIdx.x * SCAN_B + t;
    unsigned int cv = (i < n) ? cw[i] : 0u;
    const int v = (int)(cv >> 24);
    lbin[t] = 0;
    s[t] = v;
    __syncthreads();
    int lr = 0;
    if (i < n) lr = atomicAdd(&lbin[v], 1);
    __syncthreads();
    for (int off = 1; off < SCAN_B; off <<= 1) {
        int x = (t >= off) ? s[t - off] : 0;
        __syncthreads();
        s[t] += x;
        __syncthreads();
    }
    if (i < n) {
        rowptr[i] = s[t] - v;
        float d = 1.0f + (float)(cv & 0xFFFFFFu) * (1.0f / 65536.0f);
        dis[i] = rsqrtf(fmaxf(d, 1e-12f));
    }
    if (t == SCAN_B - 1) bsums[blockIdx.x] = s[t];
    int c = lbin[t];
    lbase[t] = (c > 0) ? atomicAdd(&dbin[t], c) : 0;
    __syncthreads();
    if (i < n) nrank[i] = lbase[v] + lr;
}

__global__ __launch_bounds__(256) void scan2both_kernel(int* bsums, int nb, int* dbin) {
    __shared__ int s[256];
    const int t = threadIdx.x;
    int v = (t < nb) ? bsums[t] : 0;
    s[t] = v;
    __syncthreads();
    for (int off = 1; off < 256; off <<= 1) {
        int x = (t >= off) ? s[t - off] : 0;
        __syncthreads();
        s[t] += x;
        __syncthreads();
    }
    if (t < nb) bsums[t] = s[t] - v;
    __syncthreads();
    int v2 = dbin[t];
    s[t] = v2;
    __syncthreads();
    for (int off = 1; off < 256; off <<= 1) {
        int x = (t >= off) ? s[t - off] : 0;
        __syncthreads();
        s[t] += x;
        __syncthreads();
    }
    dbin[t] = s[t] - v2;
}

__global__ void scan3_kernel(int* rowptr, const int* __restrict__ bsums,
                             const unsigned int* __restrict__ cw,
                             const int* __restrict__ nrank, const int* __restrict__ dbin,
                             int* __restrict__ perm, int n, int e) {
    int i = blockIdx.x * blockDim.x + threadIdx.x;
    if (i < n) {
        rowptr[i] += bsums[i / SCAN_B];
        unsigned int deg = cw[i] >> 24;
        perm[dbin[deg] + nrank[i]] = i;
    }
    if (i == 0) rowptr[n] = e;
}

// DIAGNOSTIC rep: idempotent rewrite, opaque-zero defeats CSE.
__global__ void fill_kernel(const int* __restrict__ row, const int* __restrict__ col,
                            const float* __restrict__ w, const float* __restrict__ dis,
                            const int* __restrict__ rowptr, const int* __restrict__ rank,
                            long long* __restrict__ epack, int e, int rep) {
    int i = blockIdx.x * blockDim.x + threadIdx.x;
    if (i >= e) return;
    const int zr = opaque_zero();
#pragma clang loop unroll(disable)
    for (int rr = 0; rr < rep; ++rr) {
        int idx = i + zr * rr;  // == i at runtime
        int r = row[idx], c = col[idx];
        float nv = dis[r] * w[idx] * dis[c];
        int dst = rowptr[r] + rank[idx];
        long long v = ((long long)__float_as_int(nv) << 32) | (unsigned int)c;
        __builtin_nontemporal_store(v, &epack[dst]);
    }
}

// ---------------- MFMA GEMM: H(bf16, OUTS-stride rows) = X @ W --------------
// DIAGNOSTIC rep: staging rewrites LDS rep times (idempotent, disjoint per
// thread); main K-loop accumulates rep passes then scales by 1/rep.
template <int KREAL, int KPAD, int F, bool IN_BF16, int INS, int OUTS>
__global__ __launch_bounds__(256) void gemm_mfma_kernel(const void* __restrict__ Xv,
                                                        const float* __restrict__ W,
                                                        unsigned short* __restrict__ H, int n,
                                                        int rep) {
    constexpr int KS = KPAD / 32;
    constexpr int NT = (F + 15) / 16;
    __shared__ unsigned short Wf[KS * NT * 64 * 8];
    const int tid = threadIdx.x;
    const int zr = opaque_zero();
#pragma clang loop unroll(disable)
    for (int rr = 0; rr < rep; ++rr) {
        for (int i = tid; i < KS * NT * 64 * 8; i += 256) {
            int ii = i + zr * rr;  // == i
            int j = ii & 7;
            int ln = (ii >> 3) & 63;
            int rest = ii >> 9;
            int nt = rest % NT;
            int ks = rest / NT;
            int k = ks * 32 + ((ln >> 4) << 3) + j;
            int c = nt * 16 + (ln & 15);
            float wv = (k < KREAL && c < F) ? W[k * F + c] : 0.f;
            Wf[ii] = f2bf(wv);
        }
    }
    __syncthreads();

    const int wid = tid >> 6;
    const int lane = tid & 63;
    const int m = lane & 15;
    const int q = lane >> 4;
    const int r0 = blockIdx.x * 64 + wid * 16;
    int rowc = r0 + m;
    if (rowc > n - 1) rowc = n - 1;  // clamp loads; stores guarded

    floatx4 acc[NT];
#pragma unroll
    for (int nt = 0; nt < NT; ++nt) acc[nt] = (floatx4){0.f, 0.f, 0.f, 0.f};

    const float* Xf = (const float*)Xv;
    const unsigned short* Xb = (const unsigned short*)Xv;
#pragma clang loop unroll(disable)
    for (int rr = 0; rr < rep; ++rr) {
        const int rowc_r = rowc + zr * rr;  // == rowc
#pragma unroll
        for (int ks = 0; ks < KS; ++ks) {
            shortx8 af;
            if constexpr (IN_BF16) {
                af = *(const shortx8*)&Xb[(size_t)rowc_r * INS + ks * 32 + q * 8];
            } else {
                const float* xp = &Xf[(size_t)rowc_r * INS + ks * 32 + q * 8];
                float4 xa = *(const float4*)xp;
                float4 xc = *(const float4*)(xp + 4);
                union { shortx8 s; unsigned int u[4]; } cv;
                cv.u[0] = ((unsigned int)f2bf(xa.y) << 16) | f2bf(xa.x);
                cv.u[1] = ((unsigned int)f2bf(xa.w) << 16) | f2bf(xa.z);
                cv.u[2] = ((unsigned int)f2bf(xc.y) << 16) | f2bf(xc.x);
                cv.u[3] = ((unsigned int)f2bf(xc.w) << 16) | f2bf(xc.z);
                af = cv.s;
            }
#pragma unroll
            for (int nt = 0; nt < NT; ++nt) {
                shortx8 bf = *(const shortx8*)&Wf[(((ks * NT) + nt) * 64 + lane) * 8 + zr * rr];
                acc[nt] = __builtin_amdgcn_mfma_f32_16x16x32_bf16(af, bf, acc[nt], 0, 0, 0);
            }
        }
    }
    const float inv = 1.0f / (float)rep;

#pragma unroll
    for (int nt = 0; nt < NT; ++nt) {
        int c = nt * 16 + m;
        if (c >= F) continue;
#pragma unroll
        for (int r = 0; r < 4; ++r) {
            int orow = r0 + q * 4 + r;
            if (orow < n) H[(size_t)orow * OUTS + c] = f2bf(acc[nt][r] * inv);
        }
    }
}

// thread-per-row GEMV for tiny F (layer 3: K=50, F=6), fp32 out stride FS.
// DIAGNOSTIC rep: accumulate rep passes, scale by 1/rep.
template <int K, int F, int FS, bool RELU_IN>
__global__ __launch_bounds__(256) void gemv_rows_kernel(const float* __restrict__ X,
                                                        const float* __restrict__ W,
                                                        float* __restrict__ H, int n,
                                                        int rep) {
    static_assert(K % 2 == 0, "K must be even");
    __shared__ float Ws[K * F];
    const int tid = threadIdx.x;
    for (int i = tid; i < K * F; i += 256) Ws[i] = W[i];
    __syncthreads();
    int r = blockIdx.x * 256 + tid;
    if (r >= n) return;
    const int zr = opaque_zero();
    float acc[F] = {};
#pragma clang loop unroll(disable)
    for (int rr = 0; rr < rep; ++rr) {
        const float* xp = X + (long long)r * K + zr * rr;  // == base
        for (int k = 0; k < K; k += 2) {
            float2 x2 = *reinterpret_cast<const float2*>(xp + k);
            if (RELU_IN) { x2.x = fmaxf(x2.x, 0.f); x2.y = fmaxf(x2.y, 0.f); }
#pragma unroll
            for (int j = 0; j < F; ++j)
                acc[j] += x2.x * Ws[k * F + j] + x2.y * Ws[(k + 1) * F + j];
        }
    }
    const float inv = 1.0f / (float)rep;
    long long base = (long long)r * FS;
#pragma unroll
    for (int j = 0; j < F; ++j) H[base + j] = acc[j] * inv;
}

// ---------------- single-pass agg, 256B bf16 rows, uint4 lanes ----------------
// rep kept from R21 (production passes rep=1).
template <int F, int RSIN, int RSOUT>
__global__ __launch_bounds__(BT) void agg_o4_kernel(const int* __restrict__ rowptr,
                                                    const int* __restrict__ perm,
                                                    const long long* __restrict__ epack,
                                                    const uint4* __restrict__ H,
                                                    const float* __restrict__ dis,
                                                    const float* __restrict__ bias,
                                                    unsigned short* __restrict__ A, int n,
                                                    int rep) {
    constexpr int TPN = 16, NPB = BT / TPN;
    constexpr int RU4 = RSIN / 8;
    const int sidx = blockIdx.x * NPB + threadIdx.x / TPN;
    const int lane = threadIdx.x & (TPN - 1);
    if (sidx >= n) return;
    const int f = 8 * lane;
    if (f >= F) return;  // fully-pad lane: no gather work at all
    const int node = perm[sidx];

    float a[8] = {};
    const int jbeg = rowptr[node];
    const int end = rowptr[node + 1];
#pragma clang loop unroll(disable)
    for (int r = 0; r < rep; ++r) {
        int j = jbeg;
        for (; j + 8 <= end; j += 8) {
            long long e[8];
            uint4 v[8];
#pragma unroll
            for (int t = 0; t < 8; ++t) e[t] = epack[j + t];
#pragma unroll
            for (int t = 0; t < 8; ++t) v[t] = H[(size_t)(int)e[t] * RU4 + lane];
#pragma unroll
            for (int t = 0; t < 8; ++t) {
                float nv = __int_as_float((int)(e[t] >> 32));
                a[0] += nv * bf_lo(v[t].x); a[1] += nv * bf_hi(v[t].x);
                a[2] += nv * bf_lo(v[t].y); a[3] += nv * bf_hi(v[t].y);
                a[4] += nv * bf_lo(v[t].z); a[5] += nv * bf_hi(v[t].z);
                a[6] += nv * bf_lo(v[t].w); a[7] += nv * bf_hi(v[t].w);
            }
        }
        for (; j < end; ++j) {
            long long ev = epack[j];
            uint4 v = H[(size_t)(int)ev * RU4 + lane];
            float nv = __int_as_float((int)(ev >> 32));
            a[0] += nv * bf_lo(v.x); a[1] += nv * bf_hi(v.x);
            a[2] += nv * bf_lo(v.y); a[3] += nv * bf_hi(v.y);
            a[4] += nv * bf_lo(v.z); a[5] += nv * bf_hi(v.z);
            a[6] += nv * bf_lo(v.w); a[7] += nv * bf_hi(v.w);
        }
    }
    const float inv = 1.0f / (float)rep;
    const int valid = F - f;  // >= 1 here
    float d = dis[node];
    float d2 = d * d;
    uint4 hs = H[(size_t)node * RU4 + lane];
    float h[8] = {bf_lo(hs.x), bf_hi(hs.x), bf_lo(hs.y), bf_hi(hs.y),
                  bf_lo(hs.z), bf_hi(hs.z), bf_lo(hs.w), bf_hi(hs.w)};
    unsigned short o[8];
#pragma unroll
    for (int k = 0; k < 8; ++k) {
        float t = (k < valid) ? fmaxf(bias[f + k] + d2 * h[k] + a[k] * inv, 0.f) : 0.f;
        o[k] = f2bf(t);
    }
    nuint4 qv;
    qv.x = ((unsigned int)o[1] << 16) | o[0];
    qv.y = ((unsigned int)o[3] << 16) | o[2];
    qv.z = ((unsigned int)o[5] << 16) | o[4];
    qv.w = ((unsigned int)o[7] << 16) | o[6];
    __builtin_nontemporal_store(qv, (nuint4*)&A[(size_t)node * RSOUT + f]);
}

// single-pass agg, 128B bf16 rows in, fp32 out (layer 2 -> gemv). f = 4*lane.
template <int F, int RSIN>
__global__ __launch_bounds__(BT) void agg_u2_kernel(const int* __restrict__ rowptr,
                                                    const int* __restrict__ perm,
                                                    const long long* __restrict__ epack,
                                                    const uint2* __restrict__ H,
                                                    const float* __restrict__ dis,
                                                    const float* __restrict__ bias,
                                                    float* __restrict__ A, int n,
                                                    int rep) {
    constexpr int TPN = 16, NPB = BT / TPN;
    constexpr int RU2 = RSIN / 4;
    const int sidx = blockIdx.x * NPB + threadIdx.x / TPN;
    const int lane = threadIdx.x & (TPN - 1);
    if (sidx >= n) return;
    const int f = 4 * lane;
    if (f >= F) return;  // fully-pad lane: skip gather entirely
    const int node = perm[sidx];

    float a0 = 0.f, a1 = 0.f, a2 = 0.f, a3 = 0.f;
    const int jbeg = rowptr[node];
    const int end = rowptr[node + 1];
#pragma clang loop unroll(disable)
    for (int r = 0; r < rep; ++r) {
        int j = jbeg;
        for (; j + 8 <= end; j += 8) {
            long long e[8];
            uint2 v[8];
#pragma unroll
            for (int t = 0; t < 8; ++t) e[t] = epack[j + t];
#pragma unroll
            for (int t = 0; t < 8; ++t) v[t] = H[(size_t)(int)e[t] * RU2 + lane];
#pragma unroll
            for (int t = 0; t < 8; ++t) {
                float nv = __int_as_float((int)(e[t] >> 32));
                a0 += nv * bf_lo(v[t].x); a1 += nv * bf_hi(v[t].x);
                a2 += nv * bf_lo(v[t].y); a3 += nv * bf_hi(v[t].y);
            }
        }
        for (; j < end; ++j) {
            long long ev = epack[j];
            uint2 v = H[(size_t)(int)ev * RU2 + lane];
            float nv = __int_as_float((int)(ev >> 32));
            a0 += nv * bf_lo(v.x); a1 += nv * bf_hi(v.x);
            a2 += nv * bf_lo(v.y); a3 += nv * bf_hi(v.y);
        }
    }
    const float inv = 1.0f / (float)rep;
    float d = dis[node];
    float d2 = d * d;
    uint2 hs = H[(size_t)node * RU2 + lane];
    float o0 = 0.f, o1 = 0.f, o2 = 0.f, o3 = 0.f;
    if (f < F) o0 = bias[f] + d2 * bf_lo(hs.x) + a0 * inv;
    if (f + 1 < F) o1 = bias[f + 1] + d2 * bf_hi(hs.x) + a1 * inv;
    if (f + 2 < F) o2 = bias[f + 2] + d2 * bf_lo(hs.y) + a2 * inv;
    if (f + 3 < F) o3 = bias[f + 3] + d2 * bf_hi(hs.y) + a3 * inv;
    float* ap = &A[(size_t)node * F + f];
    if (f + 3 < F) {
        nfloat4 q = {o0, o1, o2, o3};
        __builtin_nontemporal_store(q, (nfloat4*)ap);
    } else if (f + 1 < F) {  // F=50 tail at f=48
        nfloat2 q = {o0, o1};
        __builtin_nontemporal_store(q, (nfloat2*)ap);
    } else {
        __builtin_nontemporal_store(o0, ap);
    }
}

// per-node agg for tiny F (fp32 H, row stride 8), degree-sorted
// DIAGNOSTIC rep: accumulate rep passes, scale by 1/rep.
template <int F, int TPN>
__global__ __launch_bounds__(BT) void agg_small_kernel(const int* __restrict__ rowptr,
                                                       const int* __restrict__ perm,
                                                       const long long* __restrict__ epack,
                                                       const float* __restrict__ H,
                                                       const float* __restrict__ dis,
                                                       const float* __restrict__ bias,
                                                       float* __restrict__ A, int n,
                                                       int rep) {
    int gid = blockIdx.x * blockDim.x + threadIdx.x;
    int sidx = gid / TPN;
    int lane = threadIdx.x & (TPN - 1);
    if (sidx >= n) return;
    int node = perm[sidx];
    bool active = (lane < F);
    const int zr = opaque_zero();
    float acc = 0.f;
    const int jbeg = rowptr[node];
    const int end = rowptr[node + 1];
#pragma clang loop unroll(disable)
    for (int rr = 0; rr < rep; ++rr) {
        int j = jbeg + zr * rr;  // == jbeg
        for (; j + 4 <= end; j += 4) {
            long long e0 = epack[j + 0];
            long long e1 = epack[j + 1];
            long long e2 = epack[j + 2];
            long long e3 = epack[j + 3];
            if (active) {
                float h0 = H[(size_t)(int)e0 * 8 + lane];
                float h1 = H[(size_t)(int)e1 * 8 + lane];
                float h2 = H[(size_t)(int)e2 * 8 + lane];
                float h3 = H[(size_t)(int)e3 * 8 + lane];
                acc += __int_as_float((int)(e0 >> 32)) * h0;
                acc += __int_as_float((int)(e1 >> 32)) * h1;
                acc += __int_as_float((int)(e2 >> 32)) * h2;
                acc += __int_as_float((int)(e3 >> 32)) * h3;
            }
        }
        for (; j < end; ++j) {
            long long ev = epack[j];
            if (active) acc += __int_as_float((int)(ev >> 32)) * H[(size_t)(int)ev * 8 + lane];
        }
    }
    if (active) {
        float d = dis[node];
        float v = bias[lane] + d * d * H[(size_t)node * 8 + lane] + acc / (float)rep;
        __builtin_nontemporal_store(v, &A[(size_t)node * F + lane]);
    }
}

// ---------------------------------------------------------------------------
extern "C" void kernel_launch(void* const* d_in, const int* in_sizes, int n_in,
                              void* d_out, int out_size, void* d_ws, size_t ws_size,
                              hipStream_t stream) {
    const float* x  = (const float*)d_in[0];
    const int*   ei = (const int*)d_in[1];
    const float* ew = (const float*)d_in[2];
    const float* W0 = (const float*)d_in[3];
    const float* b0 = (const float*)d_in[4];
    const float* W1 = (const float*)d_in[5];
    const float* b1 = (const float*)d_in[6];
    const float* W2 = (const float*)d_in[7];
    const float* b2 = (const float*)d_in[8];
    const float* W3 = (const float*)d_in[9];
    const float* b3 = (const float*)d_in[10];
    float* out = (float*)d_out;

    const int N = in_sizes[0] / 128;  // 50000
    const int E = in_sizes[1] / 2;    // 800000
    const int* row = ei;
    const int* col = ei + E;

    const int NB = (N + SCAN_B - 1) / SCAN_B;
    const int blocksN = (N + BT - 1) / BT;
    const int blocksE = (E + BT - 1) / BT;

    // DIAGNOSTIC (R22): rep=4 on gemm x3, fill, gemv, agg_small; aggs rep=1.
    const int REP = 4;

    // workspace, 64B-aligned sections
    char* p = (char*)d_ws;
    auto alloc = [&](size_t bytes) {
        p = (char*)(((uintptr_t)p + 63) & ~(uintptr_t)63);
        void* r = (void*)p;
        p += bytes;
        return r;
    };
    float* dis    = (float*)alloc((size_t)N * 4);
    int*   rowptr = (int*)alloc((size_t)(N + 2) * 4);
    int*   bsums  = (int*)alloc(SCAN_B * 4);
    unsigned int* cw = (unsigned int*)alloc((size_t)(N + 256) * 4);  // cw[N] + dbin[256]
    int*   dbin   = (int*)(cw + N);
    int*   nrank  = (int*)alloc((size_t)N * 4);
    int*   perm   = (int*)alloc((size_t)N * 4);
    int*   rank   = (int*)alloc((size_t)E * 4);
    long long* epack = (long long*)alloc((size_t)E * 8);
    unsigned short* bufA = (unsigned short*)alloc((size_t)N * 128 * 2);  // H bf16, 256B rows
    unsigned short* bufB = (unsigned short*)alloc((size_t)N * 128 * 2);  // A bf16 / A3 fp32
    float* bufAf  = (float*)bufA;  // layer-3 fp32 H3[N,8] aliases bufA
    float* bufBf  = (float*)bufB;  // layer-3 fp32 A3[N,50] aliases bufB

    // ---- CSR + norm + degree-sort precompute ----
    zero_kernel<<<(N + 256 + BT - 1) / BT, BT, 0, stream>>>(cw, N + 256);
    hist_kernel<<<blocksE, BT, 0, stream>>>(row, ew, cw, rank, E);
    nodeprep_kernel<<<NB, SCAN_B, 0, stream>>>(cw, rowptr, bsums, dis, dbin, nrank, N);
    scan2both_kernel<<<1, 256, 0, stream>>>(bsums, NB, dbin);
    scan3_kernel<<<blocksN, BT, 0, stream>>>(rowptr, bsums, cw, nrank, dbin, perm, N, E);
    fill_kernel<<<blocksE, BT, 0, stream>>>(row, col, ew, dis, rowptr, rank, epack, E, REP);

    const int gemm_blocks = (N + 63) / 64;   // 64 rows/block (4 waves x 16)
    const int agg_blocks  = (N + 15) / 16;   // 16 nodes/block
    const int agg6_blocks = (N * 8 + BT - 1) / BT;

    // ---- layer 0: x fp32 (K=128) -> H bf16 100(112) cols ----
    gemm_mfma_kernel<128, 128, 100, false, 128, 128><<<gemm_blocks, 256, 0, stream>>>(x, W0, bufA, N, REP);
    agg_o4_kernel<100, 128, 128><<<agg_blocks, BT, 0, stream>>>(rowptr, perm, epack, (const uint4*)bufA, dis, b0, bufB, N, 1);

    // ---- layer 1: A1 bf16 (K=100 pad 128) -> H bf16 ----
    gemm_mfma_kernel<100, 128, 100, true, 128, 128><<<gemm_blocks, 256, 0, stream>>>(bufB, W1, bufA, N, REP);
    agg_o4_kernel<100, 128, 128><<<agg_blocks, BT, 0, stream>>>(rowptr, perm, epack, (const uint4*)bufA, dis, b1, bufB, N, 1);

    // ---- layer 2: A2 bf16 -> H bf16 50(64) cols, then agg to fp32 A3 ----
    gemm_mfma_kernel<100, 128, 50, true, 128, 64><<<gemm_blocks, 256, 0, stream>>>(bufB, W2, bufA, N, REP);
    agg_u2_kernel<50, 64><<<agg_blocks, BT, 0, stream>>>(rowptr, perm, epack, (const uint2*)bufA, dis, b2, bufBf, N, 1);

    // ---- layer 3: gemv (relu on load) + small agg ----
    gemv_rows_kernel<50, 6, 8, true><<<(N + 255) / 256, 256, 0, stream>>>(bufBf, W3, bufAf, N, REP);
    agg_small_kernel<6, 8><<<agg6_blocks, BT, 0, stream>>>(rowptr, perm, epack, bufAf, dis, b3, out, N, REP);
}

// Round 8
// 316.056 us; speedup vs baseline: 1.6947x; 1.6947x over previous
//
#include <hip/hip_runtime.h>

// ---------------------------------------------------------------------------
// GCN forward. Evidence-driven design (R4-R23):
//  - Measured budget (R21/R22 rep-diagnostics): aggs ~95us (traffic floor:
//    78MB/pass random-gather fabric @3.2TB/s), fill ~27us (NT 8B scatter ->
//    32MB/pass HBM, 5x write amplification), gemm x3 + gemv + agg_small
//    ~55us, harness workspace fill ~44us (untouchable), precompute+gaps rest.
//  - R23 fixes: (1) fill stores CACHED (L2 write-combine on row-clustered
//    dst; epack lands in L3 for aggs) -> kills the 5x amplification.
//    (2) gemv fused into layer-2 agg epilogue (per-slice shfl_xor reduce,
//    lane0 writes H3[8]-stride rows to bufB) -> -1 launch, -20MB A3 trip.
//    (3) descending-degree perm (dbin[d] = total - inclusive[d]) -> heavy
//    nodes first, no straggler tail in agg-family kernels.
//  - Ledger of refuted agg theories: slicing -20% (line traffic 2x, R16);
//    NT epack loads -5% (killed 16-edges/line L1 hits, R18); request-cut
//    neutral (R19); MLP depth 8->16 neutral (R20). Agg is at floor.
//  - GEMMs on MFMA 16x16x32 bf16, W pre-swizzled in LDS (B-frag layout),
//    C/D row=(lane>>4)*4+reg, col=lane&15; K padded, zeroed W pad rows.
//  - ONE packed 32-bit atomic per edge (count<<24|wsum fix16); rank makes
//    CSR fill atomic-free. edge (col,norm) packed i64.
// ---------------------------------------------------------------------------

#define BT 256
#define SCAN_B 256

typedef float nfloat4 __attribute__((ext_vector_type(4)));
typedef float nfloat2 __attribute__((ext_vector_type(2)));
typedef unsigned int nuint4 __attribute__((ext_vector_type(4)));
typedef __attribute__((ext_vector_type(8))) short shortx8;   // 8 bf16 (A/B frag)
typedef __attribute__((ext_vector_type(4))) float floatx4;   // C/D frag

__device__ inline float bf_lo(unsigned int v) { return __uint_as_float(v << 16); }
__device__ inline float bf_hi(unsigned int v) { return __uint_as_float(v & 0xFFFF0000u); }
__device__ inline unsigned short f2bf(float f) {  // round-to-nearest-even
    unsigned int u = __float_as_uint(f);
    unsigned int r = u + 0x7FFFu + ((u >> 16) & 1u);
    return (unsigned short)(r >> 16);
}

// ---------------- precompute ----------------
__global__ void zero_kernel(unsigned int* buf, int n) {
    int i = blockIdx.x * blockDim.x + threadIdx.x;
    if (i < n) buf[i] = 0u;
}

__global__ void hist_kernel(const int* __restrict__ row, const float* __restrict__ w,
                            unsigned int* cw, int* __restrict__ rank, int e) {
    int i = blockIdx.x * blockDim.x + threadIdx.x;
    if (i >= e) return;
    unsigned int wq = (unsigned int)(w[i] * 65536.0f + 0.5f);
    unsigned int old = atomicAdd(&cw[row[i]], (1u << 24) | wq);
    rank[i] = (int)(old >> 24);
}

// FUSED: block-scan of counts + dis + hierarchical degree histogram
__global__ __launch_bounds__(SCAN_B) void nodeprep_kernel(const unsigned int* __restrict__ cw,
                                                          int* rowptr, int* bsums, float* dis,
                                                          int* dbin, int* __restrict__ nrank,
                                                          int n) {
    __shared__ int s[SCAN_B];
    __shared__ int lbin[256];
    __shared__ int lbase[256];
    const int t = threadIdx.x;
    const int i = blockIdx.x * SCAN_B + t;
    unsigned int cv = (i < n) ? cw[i] : 0u;
    const int v = (int)(cv >> 24);
    lbin[t] = 0;
    s[t] = v;
    __syncthreads();
    int lr = 0;
    if (i < n) lr = atomicAdd(&lbin[v], 1);
    __syncthreads();
    for (int off = 1; off < SCAN_B; off <<= 1) {
        int x = (t >= off) ? s[t - off] : 0;
        __syncthreads();
        s[t] += x;
        __syncthreads();
    }
    if (i < n) {
        rowptr[i] = s[t] - v;
        float d = 1.0f + (float)(cv & 0xFFFFFFu) * (1.0f / 65536.0f);
        dis[i] = rsqrtf(fmaxf(d, 1e-12f));
    }
    if (t == SCAN_B - 1) bsums[blockIdx.x] = s[t];
    int c = lbin[t];
    lbase[t] = (c > 0) ? atomicAdd(&dbin[t], c) : 0;
    __syncthreads();
    if (i < n) nrank[i] = lbase[v] + lr;
}

// scan of per-block sums + DESCENDING scan of degree bins (R23: heavy first)
__global__ __launch_bounds__(256) void scan2both_kernel(int* bsums, int nb, int* dbin) {
    __shared__ int s[256];
    const int t = threadIdx.x;
    int v = (t < nb) ? bsums[t] : 0;
    s[t] = v;
    __syncthreads();
    for (int off = 1; off < 256; off <<= 1) {
        int x = (t >= off) ? s[t - off] : 0;
        __syncthreads();
        s[t] += x;
        __syncthreads();
    }
    if (t < nb) bsums[t] = s[t] - v;
    __syncthreads();
    int v2 = dbin[t];
    s[t] = v2;
    __syncthreads();
    for (int off = 1; off < 256; off <<= 1) {
        int x = (t >= off) ? s[t - off] : 0;
        __syncthreads();
        s[t] += x;
        __syncthreads();
    }
    // descending: offset[d] = total - inclusive[d] = sum of counts for d' > d
    dbin[t] = s[255] - s[t];
}

__global__ void scan3_kernel(int* rowptr, const int* __restrict__ bsums,
                             const unsigned int* __restrict__ cw,
                             const int* __restrict__ nrank, const int* __restrict__ dbin,
                             int* __restrict__ perm, int n, int e) {
    int i = blockIdx.x * blockDim.x + threadIdx.x;
    if (i < n) {
        rowptr[i] += bsums[i / SCAN_B];
        unsigned int deg = cw[i] >> 24;
        perm[dbin[deg] + nrank[i]] = i;
    }
    if (i == 0) rowptr[n] = e;
}

// R23: CACHED stores (was NT): 8B scatter NT stores cost 5x write
// amplification to HBM (R22: 32MB/pass for a 6.4MB buffer). Cached stores
// merge in L2 (row-clustered dst) and land in L3 for the aggs.
__global__ void fill_kernel(const int* __restrict__ row, const int* __restrict__ col,
                            const float* __restrict__ w, const float* __restrict__ dis,
                            const int* __restrict__ rowptr, const int* __restrict__ rank,
                            long long* __restrict__ epack, int e) {
    int i = blockIdx.x * blockDim.x + threadIdx.x;
    if (i >= e) return;
    int r = row[i], c = col[i];
    float nv = dis[r] * w[i] * dis[c];
    int dst = rowptr[r] + rank[i];
    epack[dst] = ((long long)__float_as_int(nv) << 32) | (unsigned int)c;
}

// ---------------- MFMA GEMM: H(bf16, OUTS-stride rows) = X @ W --------------
template <int KREAL, int KPAD, int F, bool IN_BF16, int INS, int OUTS>
__global__ __launch_bounds__(256) void gemm_mfma_kernel(const void* __restrict__ Xv,
                                                        const float* __restrict__ W,
                                                        unsigned short* __restrict__ H, int n) {
    constexpr int KS = KPAD / 32;
    constexpr int NT = (F + 15) / 16;
    __shared__ unsigned short Wf[KS * NT * 64 * 8];
    const int tid = threadIdx.x;
    for (int i = tid; i < KS * NT * 64 * 8; i += 256) {
        int j = i & 7;
        int ln = (i >> 3) & 63;
        int rest = i >> 9;
        int nt = rest % NT;
        int ks = rest / NT;
        int k = ks * 32 + ((ln >> 4) << 3) + j;
        int c = nt * 16 + (ln & 15);
        float wv = (k < KREAL && c < F) ? W[k * F + c] : 0.f;
        Wf[i] = f2bf(wv);
    }
    __syncthreads();

    const int wid = tid >> 6;
    const int lane = tid & 63;
    const int m = lane & 15;
    const int q = lane >> 4;
    const int r0 = blockIdx.x * 64 + wid * 16;
    int rowc = r0 + m;
    if (rowc > n - 1) rowc = n - 1;  // clamp loads; stores guarded

    floatx4 acc[NT];
#pragma unroll
    for (int nt = 0; nt < NT; ++nt) acc[nt] = (floatx4){0.f, 0.f, 0.f, 0.f};

    const float* Xf = (const float*)Xv;
    const unsigned short* Xb = (const unsigned short*)Xv;
#pragma unroll
    for (int ks = 0; ks < KS; ++ks) {
        shortx8 af;
        if constexpr (IN_BF16) {
            af = *(const shortx8*)&Xb[(size_t)rowc * INS + ks * 32 + q * 8];
        } else {
            const float* xp = &Xf[(size_t)rowc * INS + ks * 32 + q * 8];
            float4 xa = *(const float4*)xp;
            float4 xc = *(const float4*)(xp + 4);
            union { shortx8 s; unsigned int u[4]; } cv;
            cv.u[0] = ((unsigned int)f2bf(xa.y) << 16) | f2bf(xa.x);
            cv.u[1] = ((unsigned int)f2bf(xa.w) << 16) | f2bf(xa.z);
            cv.u[2] = ((unsigned int)f2bf(xc.y) << 16) | f2bf(xc.x);
            cv.u[3] = ((unsigned int)f2bf(xc.w) << 16) | f2bf(xc.z);
            af = cv.s;
        }
#pragma unroll
        for (int nt = 0; nt < NT; ++nt) {
            shortx8 bf = *(const shortx8*)&Wf[(((ks * NT) + nt) * 64 + lane) * 8];
            acc[nt] = __builtin_amdgcn_mfma_f32_16x16x32_bf16(af, bf, acc[nt], 0, 0, 0);
        }
    }

#pragma unroll
    for (int nt = 0; nt < NT; ++nt) {
        int c = nt * 16 + m;
        if (c >= F) continue;
#pragma unroll
        for (int r = 0; r < 4; ++r) {
            int orow = r0 + q * 4 + r;
            if (orow < n) H[(size_t)orow * OUTS + c] = f2bf(acc[nt][r]);
        }
    }
}

// ---------------- single-pass agg, 256B bf16 rows, uint4 lanes ----------------
// Output: bf16 A-rows (RSOUT ushorts, 256B) with fused ReLU - feeds MFMA GEMM.
// Pad lanes early-return; 8-deep pipeline; cached epack (16 edges/line).
template <int F, int RSIN, int RSOUT>
__global__ __launch_bounds__(BT) void agg_o4_kernel(const int* __restrict__ rowptr,
                                                    const int* __restrict__ perm,
                                                    const long long* __restrict__ epack,
                                                    const uint4* __restrict__ H,
                                                    const float* __restrict__ dis,
                                                    const float* __restrict__ bias,
                                                    unsigned short* __restrict__ A, int n) {
    constexpr int TPN = 16, NPB = BT / TPN;
    constexpr int RU4 = RSIN / 8;
    const int sidx = blockIdx.x * NPB + threadIdx.x / TPN;
    const int lane = threadIdx.x & (TPN - 1);
    if (sidx >= n) return;
    const int f = 8 * lane;
    if (f >= F) return;  // fully-pad lane: no gather work at all
    const int node = perm[sidx];

    float a[8] = {};
    int j = rowptr[node];
    const int end = rowptr[node + 1];
    for (; j + 8 <= end; j += 8) {
        long long e[8];
        uint4 v[8];
#pragma unroll
        for (int t = 0; t < 8; ++t) e[t] = epack[j + t];
#pragma unroll
        for (int t = 0; t < 8; ++t) v[t] = H[(size_t)(int)e[t] * RU4 + lane];
#pragma unroll
        for (int t = 0; t < 8; ++t) {
            float nv = __int_as_float((int)(e[t] >> 32));
            a[0] += nv * bf_lo(v[t].x); a[1] += nv * bf_hi(v[t].x);
            a[2] += nv * bf_lo(v[t].y); a[3] += nv * bf_hi(v[t].y);
            a[4] += nv * bf_lo(v[t].z); a[5] += nv * bf_hi(v[t].z);
            a[6] += nv * bf_lo(v[t].w); a[7] += nv * bf_hi(v[t].w);
        }
    }
    for (; j < end; ++j) {
        long long ev = epack[j];
        uint4 v = H[(size_t)(int)ev * RU4 + lane];
        float nv = __int_as_float((int)(ev >> 32));
        a[0] += nv * bf_lo(v.x); a[1] += nv * bf_hi(v.x);
        a[2] += nv * bf_lo(v.y); a[3] += nv * bf_hi(v.y);
        a[4] += nv * bf_lo(v.z); a[5] += nv * bf_hi(v.z);
        a[6] += nv * bf_lo(v.w); a[7] += nv * bf_hi(v.w);
    }
    const int valid = F - f;  // >= 1 here
    float d = dis[node];
    float d2 = d * d;
    uint4 hs = H[(size_t)node * RU4 + lane];
    float h[8] = {bf_lo(hs.x), bf_hi(hs.x), bf_lo(hs.y), bf_hi(hs.y),
                  bf_lo(hs.z), bf_hi(hs.z), bf_lo(hs.w), bf_hi(hs.w)};
    unsigned short o[8];
#pragma unroll
    for (int k = 0; k < 8; ++k) {
        float t = (k < valid) ? fmaxf(bias[f + k] + d2 * h[k] + a[k], 0.f) : 0.f;
        o[k] = f2bf(t);
    }
    nuint4 qv;
    qv.x = ((unsigned int)o[1] << 16) | o[0];
    qv.y = ((unsigned int)o[3] << 16) | o[2];
    qv.z = ((unsigned int)o[5] << 16) | o[4];
    qv.w = ((unsigned int)o[7] << 16) | o[6];
    __builtin_nontemporal_store(qv, (nuint4*)&A[(size_t)node * RSOUT + f]);
}

// ---- R23 FUSED layer-2 agg + layer-3 GEMV ----------------------------------
// Per 16-lane slice: gather A3 feats (f=4*lane, f<F) like agg_u2, then each
// active lane computes partial H3[j] = sum_k relu(o_k) * W3[(f+k)*FO + j],
// 4-step shfl_xor reduce over the slice, lane0 writes H3 (FSO-stride fp32).
// Eliminates the gemv kernel and the 20MB A3 round-trip.
template <int F, int RSIN, int FO, int FSO>
__global__ __launch_bounds__(BT) void agg_l2f_kernel(const int* __restrict__ rowptr,
                                                     const int* __restrict__ perm,
                                                     const long long* __restrict__ epack,
                                                     const uint2* __restrict__ H,
                                                     const float* __restrict__ dis,
                                                     const float* __restrict__ bias,
                                                     const float* __restrict__ W3,
                                                     float* __restrict__ H3, int n) {
    constexpr int TPN = 16, NPB = BT / TPN;
    constexpr int RU2 = RSIN / 4;
    __shared__ float W3s[F * FO];  // 50x6 = 300 floats
    for (int i = threadIdx.x; i < F * FO; i += BT) W3s[i] = W3[i];
    __syncthreads();

    const int sidx = blockIdx.x * NPB + threadIdx.x / TPN;
    const int lane = threadIdx.x & (TPN - 1);
    const int f = 4 * lane;
    float p[FO] = {};
    int node = -1;
    if (sidx < n) {
        node = perm[sidx];
        if (f < F) {
            float a0 = 0.f, a1 = 0.f, a2 = 0.f, a3 = 0.f;
            int j = rowptr[node];
            const int end = rowptr[node + 1];
            for (; j + 8 <= end; j += 8) {
                long long e[8];
                uint2 v[8];
#pragma unroll
                for (int t = 0; t < 8; ++t) e[t] = epack[j + t];
#pragma unroll
                for (int t = 0; t < 8; ++t) v[t] = H[(size_t)(int)e[t] * RU2 + lane];
#pragma unroll
                for (int t = 0; t < 8; ++t) {
                    float nv = __int_as_float((int)(e[t] >> 32));
                    a0 += nv * bf_lo(v[t].x); a1 += nv * bf_hi(v[t].x);
                    a2 += nv * bf_lo(v[t].y); a3 += nv * bf_hi(v[t].y);
                }
            }
            for (; j < end; ++j) {
                long long ev = epack[j];
                uint2 v = H[(size_t)(int)ev * RU2 + lane];
                float nv = __int_as_float((int)(ev >> 32));
                a0 += nv * bf_lo(v.x); a1 += nv * bf_hi(v.x);
                a2 += nv * bf_lo(v.y); a3 += nv * bf_hi(v.y);
            }
            float d = dis[node];
            float d2 = d * d;
            uint2 hs = H[(size_t)node * RU2 + lane];
            float o[4] = {bias[f] + d2 * bf_lo(hs.x) + a0,
                          (f + 1 < F) ? bias[f + 1] + d2 * bf_hi(hs.x) + a1 : 0.f,
                          (f + 2 < F) ? bias[f + 2] + d2 * bf_lo(hs.y) + a2 : 0.f,
                          (f + 3 < F) ? bias[f + 3] + d2 * bf_hi(hs.y) + a3 : 0.f};
#pragma unroll
            for (int k = 0; k < 4; ++k) {
                if (f + k < F) {
                    float r = fmaxf(o[k], 0.f);  // relu (layer-3 input)
#pragma unroll
                    for (int jj = 0; jj < FO; ++jj)
                        p[jj] += r * W3s[(f + k) * FO + jj];
                }
            }
        }
    }
    // slice-wide reduction (all lanes participate; inactive contributed 0)
#pragma unroll
    for (int jj = 0; jj < FO; ++jj) {
        p[jj] += __shfl_xor(p[jj], 1, 16);
        p[jj] += __shfl_xor(p[jj], 2, 16);
        p[jj] += __shfl_xor(p[jj], 4, 16);
        p[jj] += __shfl_xor(p[jj], 8, 16);
    }
    if (sidx < n && lane == 0) {
        nfloat4 q0 = {p[0], p[1], p[2], p[3]};
        nfloat4 q1 = {p[4], p[5], 0.f, 0.f};
        *(nfloat4*)&H3[(size_t)node * FSO] = q0;
        *(nfloat4*)&H3[(size_t)node * FSO + 4] = q1;
    }
}

// per-node agg for tiny F (fp32 H, row stride 8), degree-sorted
template <int F, int TPN>
__global__ __launch_bounds__(BT) void agg_small_kernel(const int* __restrict__ rowptr,
                                                       const int* __restrict__ perm,
                                                       const long long* __restrict__ epack,
                                                       const float* __restrict__ H,
                                                       const float* __restrict__ dis,
                                                       const float* __restrict__ bias,
                                                       float* __restrict__ A, int n) {
    int gid = blockIdx.x * blockDim.x + threadIdx.x;
    int sidx = gid / TPN;
    int lane = threadIdx.x & (TPN - 1);
    if (sidx >= n) return;
    int node = perm[sidx];
    bool active = (lane < F);
    float acc = 0.f;
    int j = rowptr[node];
    const int end = rowptr[node + 1];
    for (; j + 4 <= end; j += 4) {
        long long e0 = epack[j + 0];
        long long e1 = epack[j + 1];
        long long e2 = epack[j + 2];
        long long e3 = epack[j + 3];
        if (active) {
            float h0 = H[(size_t)(int)e0 * 8 + lane];
            float h1 = H[(size_t)(int)e1 * 8 + lane];
            float h2 = H[(size_t)(int)e2 * 8 + lane];
            float h3 = H[(size_t)(int)e3 * 8 + lane];
            acc += __int_as_float((int)(e0 >> 32)) * h0;
            acc += __int_as_float((int)(e1 >> 32)) * h1;
            acc += __int_as_float((int)(e2 >> 32)) * h2;
            acc += __int_as_float((int)(e3 >> 32)) * h3;
        }
    }
    for (; j < end; ++j) {
        long long ev = epack[j];
        if (active) acc += __int_as_float((int)(ev >> 32)) * H[(size_t)(int)ev * 8 + lane];
    }
    if (active) {
        float d = dis[node];
        float v = bias[lane] + d * d * H[(size_t)node * 8 + lane] + acc;
        __builtin_nontemporal_store(v, &A[(size_t)node * F + lane]);
    }
}

// ---------------------------------------------------------------------------
extern "C" void kernel_launch(void* const* d_in, const int* in_sizes, int n_in,
                              void* d_out, int out_size, void* d_ws, size_t ws_size,
                              hipStream_t stream) {
    const float* x  = (const float*)d_in[0];
    const int*   ei = (const int*)d_in[1];
    const float* ew = (const float*)d_in[2];
    const float* W0 = (const float*)d_in[3];
    const float* b0 = (const float*)d_in[4];
    const float* W1 = (const float*)d_in[5];
    const float* b1 = (const float*)d_in[6];
    const float* W2 = (const float*)d_in[7];
    const float* b2 = (const float*)d_in[8];
    const float* W3 = (const float*)d_in[9];
    const float* b3 = (const float*)d_in[10];
    float* out = (float*)d_out;

    const int N = in_sizes[0] / 128;  // 50000
    const int E = in_sizes[1] / 2;    // 800000
    const int* row = ei;
    const int* col = ei + E;

    const int NB = (N + SCAN_B - 1) / SCAN_B;
    const int blocksN = (N + BT - 1) / BT;
    const int blocksE = (E + BT - 1) / BT;

    // workspace, 64B-aligned sections
    char* p = (char*)d_ws;
    auto alloc = [&](size_t bytes) {
        p = (char*)(((uintptr_t)p + 63) & ~(uintptr_t)63);
        void* r = (void*)p;
        p += bytes;
        return r;
    };
    float* dis    = (float*)alloc((size_t)N * 4);
    int*   rowptr = (int*)alloc((size_t)(N + 2) * 4);
    int*   bsums  = (int*)alloc(SCAN_B * 4);
    unsigned int* cw = (unsigned int*)alloc((size_t)(N + 256) * 4);  // cw[N] + dbin[256]
    int*   dbin   = (int*)(cw + N);
    int*   nrank  = (int*)alloc((size_t)N * 4);
    int*   perm   = (int*)alloc((size_t)N * 4);
    int*   rank   = (int*)alloc((size_t)E * 4);
    long long* epack = (long long*)alloc((size_t)E * 8);
    unsigned short* bufA = (unsigned short*)alloc((size_t)N * 128 * 2);  // H bf16, 256B rows
    unsigned short* bufB = (unsigned short*)alloc((size_t)N * 128 * 2);  // A bf16 / H3 fp32
    float* bufBf  = (float*)bufB;  // layer-3 fp32 H3[N,8] aliases bufB

    // ---- CSR + norm + degree-sort precompute ----
    zero_kernel<<<(N + 256 + BT - 1) / BT, BT, 0, stream>>>(cw, N + 256);
    hist_kernel<<<blocksE, BT, 0, stream>>>(row, ew, cw, rank, E);
    nodeprep_kernel<<<NB, SCAN_B, 0, stream>>>(cw, rowptr, bsums, dis, dbin, nrank, N);
    scan2both_kernel<<<1, 256, 0, stream>>>(bsums, NB, dbin);
    scan3_kernel<<<blocksN, BT, 0, stream>>>(rowptr, bsums, cw, nrank, dbin, perm, N, E);
    fill_kernel<<<blocksE, BT, 0, stream>>>(row, col, ew, dis, rowptr, rank, epack, E);

    const int gemm_blocks = (N + 63) / 64;   // 64 rows/block (4 waves x 16)
    const int agg_blocks  = (N + 15) / 16;   // 16 nodes/block
    const int agg6_blocks = (N * 8 + BT - 1) / BT;

    // ---- layer 0: x fp32 (K=128) -> H bf16 100(112) cols ----
    gemm_mfma_kernel<128, 128, 100, false, 128, 128><<<gemm_blocks, 256, 0, stream>>>(x, W0, bufA, N);
    agg_o4_kernel<100, 128, 128><<<agg_blocks, BT, 0, stream>>>(rowptr, perm, epack, (const uint4*)bufA, dis, b0, bufB, N);

    // ---- layer 1: A1 bf16 (K=100 pad 128) -> H bf16 ----
    gemm_mfma_kernel<100, 128, 100, true, 128, 128><<<gemm_blocks, 256, 0, stream>>>(bufB, W1, bufA, N);
    agg_o4_kernel<100, 128, 128><<<agg_blocks, BT, 0, stream>>>(rowptr, perm, epack, (const uint4*)bufA, dis, b1, bufB, N);

    // ---- layer 2: A2 bf16 -> H2 bf16 50(64) cols ----
    gemm_mfma_kernel<100, 128, 50, true, 128, 64><<<gemm_blocks, 256, 0, stream>>>(bufB, W2, bufA, N);

    // ---- FUSED layer-2 agg + layer-3 gemv: H2 -> H3 (fp32, stride 8, bufB) ----
    agg_l2f_kernel<50, 64, 6, 8><<<agg_blocks, BT, 0, stream>>>(rowptr, perm, epack, (const uint2*)bufA, dis, b2, W3, bufBf, N);

    // ---- layer 3 aggregation -> out ----
    agg_small_kernel<6, 8><<<agg6_blocks, BT, 0, stream>>>(rowptr, perm, epack, bufBf, dis, b3, out, N);
}

// Round 9
// 291.632 us; speedup vs baseline: 1.8366x; 1.0838x over previous
//
#include <hip/hip_runtime.h>

// ---------------------------------------------------------------------------
// GCN forward. Evidence-driven design (R4-R24):
//  - Measured budget (R21/R22 rep-diagnostics, R23 fixes): aggs ~110us
//    (random-gather fabric floor @3.2TB/s, 4 refuted levers: slicing -20%,
//    NT epack -5%, request-cut 0, MLP-depth 0), GEMMs ~28, fill ~15,
//    fused-L3 ~20, precompute ~25, gaps ~30, harness fill ~44 (untouchable).
//  - R23 (-17us): cached fill stores (killed 5x NT write amplification),
//    gemv fused into layer-2 agg, descending-degree perm.
//  - R24: (1) GEMM 512-thread/128-row blocks - W-staging (14336 LDS elems +
//    f2bf) is per-block and dominated the 112-MFMA compute; 2x rows halves
//    staging/row. (2) fill fused into gemm0 launch (independent inputs;
//    stripe-interleaved 1:4 block roles) - overlaps ~15us fill under gemm0,
//    -1 launch.
//  - GEMMs on MFMA 16x16x32 bf16, W pre-swizzled in LDS (B-frag layout),
//    C/D row=(lane>>4)*4+reg, col=lane&15; K padded, zeroed W pad rows.
//  - agg: single pass, 256B bf16 rows, TPN=16 x uint4, 8-deep pipeline,
//    cached epack (16 edges/line), NT stores on write-only outputs.
//  - ONE packed 32-bit atomic per edge (count<<24|wsum fix16); rank makes
//    CSR fill atomic-free. edge (col,norm) packed i64.
// ---------------------------------------------------------------------------

#define BT 256
#define SCAN_B 256

typedef float nfloat4 __attribute__((ext_vector_type(4)));
typedef float nfloat2 __attribute__((ext_vector_type(2)));
typedef unsigned int nuint4 __attribute__((ext_vector_type(4)));
typedef __attribute__((ext_vector_type(8))) short shortx8;   // 8 bf16 (A/B frag)
typedef __attribute__((ext_vector_type(4))) float floatx4;   // C/D frag

__device__ inline float bf_lo(unsigned int v) { return __uint_as_float(v << 16); }
__device__ inline float bf_hi(unsigned int v) { return __uint_as_float(v & 0xFFFF0000u); }
__device__ inline unsigned short f2bf(float f) {  // round-to-nearest-even
    unsigned int u = __float_as_uint(f);
    unsigned int r = u + 0x7FFFu + ((u >> 16) & 1u);
    return (unsigned short)(r >> 16);
}

// ---------------- precompute ----------------
__global__ void zero_kernel(unsigned int* buf, int n) {
    int i = blockIdx.x * blockDim.x + threadIdx.x;
    if (i < n) buf[i] = 0u;
}

__global__ void hist_kernel(const int* __restrict__ row, const float* __restrict__ w,
                            unsigned int* cw, int* __restrict__ rank, int e) {
    int i = blockIdx.x * blockDim.x + threadIdx.x;
    if (i >= e) return;
    unsigned int wq = (unsigned int)(w[i] * 65536.0f + 0.5f);
    unsigned int old = atomicAdd(&cw[row[i]], (1u << 24) | wq);
    rank[i] = (int)(old >> 24);
}

// FUSED: block-scan of counts + dis + hierarchical degree histogram
__global__ __launch_bounds__(SCAN_B) void nodeprep_kernel(const unsigned int* __restrict__ cw,
                                                          int* rowptr, int* bsums, float* dis,
                                                          int* dbin, int* __restrict__ nrank,
                                                          int n) {
    __shared__ int s[SCAN_B];
    __shared__ int lbin[256];
    __shared__ int lbase[256];
    const int t = threadIdx.x;
    const int i = blockIdx.x * SCAN_B + t;
    unsigned int cv = (i < n) ? cw[i] : 0u;
    const int v = (int)(cv >> 24);
    lbin[t] = 0;
    s[t] = v;
    __syncthreads();
    int lr = 0;
    if (i < n) lr = atomicAdd(&lbin[v], 1);
    __syncthreads();
    for (int off = 1; off < SCAN_B; off <<= 1) {
        int x = (t >= off) ? s[t - off] : 0;
        __syncthreads();
        s[t] += x;
        __syncthreads();
    }
    if (i < n) {
        rowptr[i] = s[t] - v;
        float d = 1.0f + (float)(cv & 0xFFFFFFu) * (1.0f / 65536.0f);
        dis[i] = rsqrtf(fmaxf(d, 1e-12f));
    }
    if (t == SCAN_B - 1) bsums[blockIdx.x] = s[t];
    int c = lbin[t];
    lbase[t] = (c > 0) ? atomicAdd(&dbin[t], c) : 0;
    __syncthreads();
    if (i < n) nrank[i] = lbase[v] + lr;
}

// scan of per-block sums + DESCENDING scan of degree bins (heavy first)
__global__ __launch_bounds__(256) void scan2both_kernel(int* bsums, int nb, int* dbin) {
    __shared__ int s[256];
    const int t = threadIdx.x;
    int v = (t < nb) ? bsums[t] : 0;
    s[t] = v;
    __syncthreads();
    for (int off = 1; off < 256; off <<= 1) {
        int x = (t >= off) ? s[t - off] : 0;
        __syncthreads();
        s[t] += x;
        __syncthreads();
    }
    if (t < nb) bsums[t] = s[t] - v;
    __syncthreads();
    int v2 = dbin[t];
    s[t] = v2;
    __syncthreads();
    for (int off = 1; off < 256; off <<= 1) {
        int x = (t >= off) ? s[t - off] : 0;
        __syncthreads();
        s[t] += x;
        __syncthreads();
    }
    // descending: offset[d] = total - inclusive[d] = sum of counts for d' > d
    dbin[t] = s[255] - s[t];
}

__global__ void scan3_kernel(int* rowptr, const int* __restrict__ bsums,
                             const unsigned int* __restrict__ cw,
                             const int* __restrict__ nrank, const int* __restrict__ dbin,
                             int* __restrict__ perm, int n, int e) {
    int i = blockIdx.x * blockDim.x + threadIdx.x;
    if (i < n) {
        rowptr[i] += bsums[i / SCAN_B];
        unsigned int deg = cw[i] >> 24;
        perm[dbin[deg] + nrank[i]] = i;
    }
    if (i == 0) rowptr[n] = e;
}

// ---------------- MFMA GEMM body (shared by plain + fused kernels) ----------
// 512 threads = 8 waves x 16 rows = 128 rows/block (R24: halves per-row
// W-staging cost vs 64-row blocks). Cached stores merged via L2.
template <int KREAL, int KPAD, int F, bool IN_BF16, int INS, int OUTS>
__device__ __forceinline__ void gemm_body(const void* __restrict__ Xv,
                                          const float* __restrict__ W,
                                          unsigned short* __restrict__ H, int n,
                                          int gb, int tid) {
    constexpr int KS = KPAD / 32;
    constexpr int NT = (F + 15) / 16;
    __shared__ unsigned short Wf[KS * NT * 64 * 8];
    for (int i = tid; i < KS * NT * 64 * 8; i += 512) {
        int j = i & 7;
        int ln = (i >> 3) & 63;
        int rest = i >> 9;
        int nt = rest % NT;
        int ks = rest / NT;
        int k = ks * 32 + ((ln >> 4) << 3) + j;
        int c = nt * 16 + (ln & 15);
        float wv = (k < KREAL && c < F) ? W[k * F + c] : 0.f;
        Wf[i] = f2bf(wv);
    }
    __syncthreads();

    const int wid = tid >> 6;
    const int lane = tid & 63;
    const int m = lane & 15;
    const int q = lane >> 4;
    const int r0 = gb * 128 + wid * 16;
    int rowc = r0 + m;
    if (rowc > n - 1) rowc = n - 1;  // clamp loads; stores guarded

    floatx4 acc[NT];
#pragma unroll
    for (int nt = 0; nt < NT; ++nt) acc[nt] = (floatx4){0.f, 0.f, 0.f, 0.f};

    const float* Xf = (const float*)Xv;
    const unsigned short* Xb = (const unsigned short*)Xv;
#pragma unroll
    for (int ks = 0; ks < KS; ++ks) {
        shortx8 af;
        if constexpr (IN_BF16) {
            af = *(const shortx8*)&Xb[(size_t)rowc * INS + ks * 32 + q * 8];
        } else {
            const float* xp = &Xf[(size_t)rowc * INS + ks * 32 + q * 8];
            float4 xa = *(const float4*)xp;
            float4 xc = *(const float4*)(xp + 4);
            union { shortx8 s; unsigned int u[4]; } cv;
            cv.u[0] = ((unsigned int)f2bf(xa.y) << 16) | f2bf(xa.x);
            cv.u[1] = ((unsigned int)f2bf(xa.w) << 16) | f2bf(xa.z);
            cv.u[2] = ((unsigned int)f2bf(xc.y) << 16) | f2bf(xc.x);
            cv.u[3] = ((unsigned int)f2bf(xc.w) << 16) | f2bf(xc.z);
            af = cv.s;
        }
#pragma unroll
        for (int nt = 0; nt < NT; ++nt) {
            shortx8 bf = *(const shortx8*)&Wf[(((ks * NT) + nt) * 64 + lane) * 8];
            acc[nt] = __builtin_amdgcn_mfma_f32_16x16x32_bf16(af, bf, acc[nt], 0, 0, 0);
        }
    }

#pragma unroll
    for (int nt = 0; nt < NT; ++nt) {
        int c = nt * 16 + m;
        if (c >= F) continue;
#pragma unroll
        for (int r = 0; r < 4; ++r) {
            int orow = r0 + q * 4 + r;
            if (orow < n) H[(size_t)orow * OUTS + c] = f2bf(acc[nt][r]);
        }
    }
}

template <int KREAL, int KPAD, int F, bool IN_BF16, int INS, int OUTS>
__global__ __launch_bounds__(512) void gemm_mfma_kernel(const void* __restrict__ Xv,
                                                        const float* __restrict__ W,
                                                        unsigned short* __restrict__ H, int n) {
    gemm_body<KREAL, KPAD, F, IN_BF16, INS, OUTS>(Xv, W, H, n, blockIdx.x, threadIdx.x);
}

// R24 FUSED: layer-0 GEMM + CSR fill in one heterogeneous grid. Independent
// inputs (gemm: x,W0; fill: scan3 outputs). Stripe 1:4 so both progress
// concurrently. Whole blocks take one branch (gemm's __syncthreads safe).
template <int KREAL, int KPAD, int F, int INS, int OUTS>
__global__ __launch_bounds__(512) void gemm0_fill_kernel(const void* __restrict__ Xv,
                                                         const float* __restrict__ W,
                                                         unsigned short* __restrict__ H, int n,
                                                         int gemmB,
                                                         const int* __restrict__ row,
                                                         const int* __restrict__ col,
                                                         const float* __restrict__ w,
                                                         const float* __restrict__ dis,
                                                         const int* __restrict__ rowptr,
                                                         const int* __restrict__ rank,
                                                         long long* __restrict__ epack, int e) {
    const int b = blockIdx.x;
    const bool isg = (b % 5 == 0) && (b / 5 < gemmB);
    if (isg) {
        gemm_body<KREAL, KPAD, F, false, INS, OUTS>(Xv, W, H, n, b / 5, threadIdx.x);
    } else {
        const int npre = (b / 5 + 1 < gemmB) ? (b / 5 + 1) : gemmB;  // gemm blocks <= b
        const int fid = b - npre;
        const int i = fid * 512 + (int)threadIdx.x;
        if (i < e) {
            int r = row[i], c = col[i];
            float nv = dis[r] * w[i] * dis[c];
            int dst = rowptr[r] + rank[i];
            epack[dst] = ((long long)__float_as_int(nv) << 32) | (unsigned int)c;
        }
    }
}

// ---------------- single-pass agg, 256B bf16 rows, uint4 lanes ----------------
// Output: bf16 A-rows (RSOUT ushorts, 256B) with fused ReLU - feeds MFMA GEMM.
// Pad lanes early-return; 8-deep pipeline; cached epack (16 edges/line).
template <int F, int RSIN, int RSOUT>
__global__ __launch_bounds__(BT) void agg_o4_kernel(const int* __restrict__ rowptr,
                                                    const int* __restrict__ perm,
                                                    const long long* __restrict__ epack,
                                                    const uint4* __restrict__ H,
                                                    const float* __restrict__ dis,
                                                    const float* __restrict__ bias,
                                                    unsigned short* __restrict__ A, int n) {
    constexpr int TPN = 16, NPB = BT / TPN;
    constexpr int RU4 = RSIN / 8;
    const int sidx = blockIdx.x * NPB + threadIdx.x / TPN;
    const int lane = threadIdx.x & (TPN - 1);
    if (sidx >= n) return;
    const int f = 8 * lane;
    if (f >= F) return;  // fully-pad lane: no gather work at all
    const int node = perm[sidx];

    float a[8] = {};
    int j = rowptr[node];
    const int end = rowptr[node + 1];
    for (; j + 8 <= end; j += 8) {
        long long e[8];
        uint4 v[8];
#pragma unroll
        for (int t = 0; t < 8; ++t) e[t] = epack[j + t];
#pragma unroll
        for (int t = 0; t < 8; ++t) v[t] = H[(size_t)(int)e[t] * RU4 + lane];
#pragma unroll
        for (int t = 0; t < 8; ++t) {
            float nv = __int_as_float((int)(e[t] >> 32));
            a[0] += nv * bf_lo(v[t].x); a[1] += nv * bf_hi(v[t].x);
            a[2] += nv * bf_lo(v[t].y); a[3] += nv * bf_hi(v[t].y);
            a[4] += nv * bf_lo(v[t].z); a[5] += nv * bf_hi(v[t].z);
            a[6] += nv * bf_lo(v[t].w); a[7] += nv * bf_hi(v[t].w);
        }
    }
    for (; j < end; ++j) {
        long long ev = epack[j];
        uint4 v = H[(size_t)(int)ev * RU4 + lane];
        float nv = __int_as_float((int)(ev >> 32));
        a[0] += nv * bf_lo(v.x); a[1] += nv * bf_hi(v.x);
        a[2] += nv * bf_lo(v.y); a[3] += nv * bf_hi(v.y);
        a[4] += nv * bf_lo(v.z); a[5] += nv * bf_hi(v.z);
        a[6] += nv * bf_lo(v.w); a[7] += nv * bf_hi(v.w);
    }
    const int valid = F - f;  // >= 1 here
    float d = dis[node];
    float d2 = d * d;
    uint4 hs = H[(size_t)node * RU4 + lane];
    float h[8] = {bf_lo(hs.x), bf_hi(hs.x), bf_lo(hs.y), bf_hi(hs.y),
                  bf_lo(hs.z), bf_hi(hs.z), bf_lo(hs.w), bf_hi(hs.w)};
    unsigned short o[8];
#pragma unroll
    for (int k = 0; k < 8; ++k) {
        float t = (k < valid) ? fmaxf(bias[f + k] + d2 * h[k] + a[k], 0.f) : 0.f;
        o[k] = f2bf(t);
    }
    nuint4 qv;
    qv.x = ((unsigned int)o[1] << 16) | o[0];
    qv.y = ((unsigned int)o[3] << 16) | o[2];
    qv.z = ((unsigned int)o[5] << 16) | o[4];
    qv.w = ((unsigned int)o[7] << 16) | o[6];
    __builtin_nontemporal_store(qv, (nuint4*)&A[(size_t)node * RSOUT + f]);
}

// ---- FUSED layer-2 agg + layer-3 GEMV --------------------------------------
// Per 16-lane slice: gather A3 feats (f=4*lane, f<F) like agg_u2, then each
// active lane computes partial H3[j] = sum_k relu(o_k) * W3[(f+k)*FO + j],
// 4-step shfl_xor reduce over the slice, lane0 writes H3 (FSO-stride fp32).
template <int F, int RSIN, int FO, int FSO>
__global__ __launch_bounds__(BT) void agg_l2f_kernel(const int* __restrict__ rowptr,
                                                     const int* __restrict__ perm,
                                                     const long long* __restrict__ epack,
                                                     const uint2* __restrict__ H,
                                                     const float* __restrict__ dis,
                                                     const float* __restrict__ bias,
                                                     const float* __restrict__ W3,
                                                     float* __restrict__ H3, int n) {
    constexpr int TPN = 16, NPB = BT / TPN;
    constexpr int RU2 = RSIN / 4;
    __shared__ float W3s[F * FO];  // 50x6 = 300 floats
    for (int i = threadIdx.x; i < F * FO; i += BT) W3s[i] = W3[i];
    __syncthreads();

    const int sidx = blockIdx.x * NPB + threadIdx.x / TPN;
    const int lane = threadIdx.x & (TPN - 1);
    const int f = 4 * lane;
    float p[FO] = {};
    int node = -1;
    if (sidx < n) {
        node = perm[sidx];
        if (f < F) {
            float a0 = 0.f, a1 = 0.f, a2 = 0.f, a3 = 0.f;
            int j = rowptr[node];
            const int end = rowptr[node + 1];
            for (; j + 8 <= end; j += 8) {
                long long e[8];
                uint2 v[8];
#pragma unroll
                for (int t = 0; t < 8; ++t) e[t] = epack[j + t];
#pragma unroll
                for (int t = 0; t < 8; ++t) v[t] = H[(size_t)(int)e[t] * RU2 + lane];
#pragma unroll
                for (int t = 0; t < 8; ++t) {
                    float nv = __int_as_float((int)(e[t] >> 32));
                    a0 += nv * bf_lo(v[t].x); a1 += nv * bf_hi(v[t].x);
                    a2 += nv * bf_lo(v[t].y); a3 += nv * bf_hi(v[t].y);
                }
            }
            for (; j < end; ++j) {
                long long ev = epack[j];
                uint2 v = H[(size_t)(int)ev * RU2 + lane];
                float nv = __int_as_float((int)(ev >> 32));
                a0 += nv * bf_lo(v.x); a1 += nv * bf_hi(v.x);
                a2 += nv * bf_lo(v.y); a3 += nv * bf_hi(v.y);
            }
            float d = dis[node];
            float d2 = d * d;
            uint2 hs = H[(size_t)node * RU2 + lane];
            float o[4] = {bias[f] + d2 * bf_lo(hs.x) + a0,
                          (f + 1 < F) ? bias[f + 1] + d2 * bf_hi(hs.x) + a1 : 0.f,
                          (f + 2 < F) ? bias[f + 2] + d2 * bf_lo(hs.y) + a2 : 0.f,
                          (f + 3 < F) ? bias[f + 3] + d2 * bf_hi(hs.y) + a3 : 0.f};
#pragma unroll
            for (int k = 0; k < 4; ++k) {
                if (f + k < F) {
                    float r = fmaxf(o[k], 0.f);  // relu (layer-3 input)
#pragma unroll
                    for (int jj = 0; jj < FO; ++jj)
                        p[jj] += r * W3s[(f + k) * FO + jj];
                }
            }
        }
    }
    // slice-wide reduction (all lanes participate; inactive contributed 0)
#pragma unroll
    for (int jj = 0; jj < FO; ++jj) {
        p[jj] += __shfl_xor(p[jj], 1, 16);
        p[jj] += __shfl_xor(p[jj], 2, 16);
        p[jj] += __shfl_xor(p[jj], 4, 16);
        p[jj] += __shfl_xor(p[jj], 8, 16);
    }
    if (sidx < n && lane == 0) {
        nfloat4 q0 = {p[0], p[1], p[2], p[3]};
        nfloat4 q1 = {p[4], p[5], 0.f, 0.f};
        *(nfloat4*)&H3[(size_t)node * FSO] = q0;
        *(nfloat4*)&H3[(size_t)node * FSO + 4] = q1;
    }
}

// per-node agg for tiny F (fp32 H, row stride 8), degree-sorted
template <int F, int TPN>
__global__ __launch_bounds__(BT) void agg_small_kernel(const int* __restrict__ rowptr,
                                                       const int* __restrict__ perm,
                                                       const long long* __restrict__ epack,
                                                       const float* __restrict__ H,
                                                       const float* __restrict__ dis,
                                                       const float* __restrict__ bias,
                                                       float* __restrict__ A, int n) {
    int gid = blockIdx.x * blockDim.x + threadIdx.x;
    int sidx = gid / TPN;
    int lane = threadIdx.x & (TPN - 1);
    if (sidx >= n) return;
    int node = perm[sidx];
    bool active = (lane < F);
    float acc = 0.f;
    int j = rowptr[node];
    const int end = rowptr[node + 1];
    for (; j + 4 <= end; j += 4) {
        long long e0 = epack[j + 0];
        long long e1 = epack[j + 1];
        long long e2 = epack[j + 2];
        long long e3 = epack[j + 3];
        if (active) {
            float h0 = H[(size_t)(int)e0 * 8 + lane];
            float h1 = H[(size_t)(int)e1 * 8 + lane];
            float h2 = H[(size_t)(int)e2 * 8 + lane];
            float h3 = H[(size_t)(int)e3 * 8 + lane];
            acc += __int_as_float((int)(e0 >> 32)) * h0;
            acc += __int_as_float((int)(e1 >> 32)) * h1;
            acc += __int_as_float((int)(e2 >> 32)) * h2;
            acc += __int_as_float((int)(e3 >> 32)) * h3;
        }
    }
    for (; j < end; ++j) {
        long long ev = epack[j];
        if (active) acc += __int_as_float((int)(ev >> 32)) * H[(size_t)(int)ev * 8 + lane];
    }
    if (active) {
        float d = dis[node];
        float v = bias[lane] + d * d * H[(size_t)node * 8 + lane] + acc;
        __builtin_nontemporal_store(v, &A[(size_t)node * F + lane]);
    }
}

// ---------------------------------------------------------------------------
extern "C" void kernel_launch(void* const* d_in, const int* in_sizes, int n_in,
                              void* d_out, int out_size, void* d_ws, size_t ws_size,
                              hipStream_t stream) {
    const float* x  = (const float*)d_in[0];
    const int*   ei = (const int*)d_in[1];
    const float* ew = (const float*)d_in[2];
    const float* W0 = (const float*)d_in[3];
    const float* b0 = (const float*)d_in[4];
    const float* W1 = (const float*)d_in[5];
    const float* b1 = (const float*)d_in[6];
    const float* W2 = (const float*)d_in[7];
    const float* b2 = (const float*)d_in[8];
    const float* W3 = (const float*)d_in[9];
    const float* b3 = (const float*)d_in[10];
    float* out = (float*)d_out;

    const int N = in_sizes[0] / 128;  // 50000
    const int E = in_sizes[1] / 2;    // 800000
    const int* row = ei;
    const int* col = ei + E;

    const int NB = (N + SCAN_B - 1) / SCAN_B;
    const int blocksN = (N + BT - 1) / BT;
    const int blocksE = (E + BT - 1) / BT;

    // workspace, 64B-aligned sections
    char* p = (char*)d_ws;
    auto alloc = [&](size_t bytes) {
        p = (char*)(((uintptr_t)p + 63) & ~(uintptr_t)63);
        void* r = (void*)p;
        p += bytes;
        return r;
    };
    float* dis    = (float*)alloc((size_t)N * 4);
    int*   rowptr = (int*)alloc((size_t)(N + 2) * 4);
    int*   bsums  = (int*)alloc(SCAN_B * 4);
    unsigned int* cw = (unsigned int*)alloc((size_t)(N + 256) * 4);  // cw[N] + dbin[256]
    int*   dbin   = (int*)(cw + N);
    int*   nrank  = (int*)alloc((size_t)N * 4);
    int*   perm   = (int*)alloc((size_t)N * 4);
    int*   rank   = (int*)alloc((size_t)E * 4);
    long long* epack = (long long*)alloc((size_t)E * 8);
    unsigned short* bufA = (unsigned short*)alloc((size_t)N * 128 * 2);  // H bf16, 256B rows
    unsigned short* bufB = (unsigned short*)alloc((size_t)N * 128 * 2);  // A bf16 / H3 fp32
    float* bufBf  = (float*)bufB;  // layer-3 fp32 H3[N,8] aliases bufB

    // ---- CSR + norm + degree-sort precompute ----
    zero_kernel<<<(N + 256 + BT - 1) / BT, BT, 0, stream>>>(cw, N + 256);
    hist_kernel<<<blocksE, BT, 0, stream>>>(row, ew, cw, rank, E);
    nodeprep_kernel<<<NB, SCAN_B, 0, stream>>>(cw, rowptr, bsums, dis, dbin, nrank, N);
    scan2both_kernel<<<1, 256, 0, stream>>>(bsums, NB, dbin);
    scan3_kernel<<<blocksN, BT, 0, stream>>>(rowptr, bsums, cw, nrank, dbin, perm, N, E);

    const int gemmB = (N + 127) / 128;        // 128 rows/block (8 waves x 16)
    const int fillB = (E + 511) / 512;
    const int agg_blocks  = (N + 15) / 16;    // 16 nodes/block
    const int agg6_blocks = (N * 8 + BT - 1) / BT;

    // ---- layer 0 GEMM + CSR fill (independent; fused heterogeneous grid) ----
    gemm0_fill_kernel<128, 128, 100, 128, 128><<<gemmB + fillB, 512, 0, stream>>>(
        x, W0, bufA, N, gemmB, row, col, ew, dis, rowptr, rank, epack, E);
    agg_o4_kernel<100, 128, 128><<<agg_blocks, BT, 0, stream>>>(rowptr, perm, epack, (const uint4*)bufA, dis, b0, bufB, N);

    // ---- layer 1: A1 bf16 (K=100 pad 128) -> H bf16 ----
    gemm_mfma_kernel<100, 128, 100, true, 128, 128><<<gemmB, 512, 0, stream>>>(bufB, W1, bufA, N);
    agg_o4_kernel<100, 128, 128><<<agg_blocks, BT, 0, stream>>>(rowptr, perm, epack, (const uint4*)bufA, dis, b1, bufB, N);

    // ---- layer 2: A2 bf16 -> H2 bf16 50(64) cols ----
    gemm_mfma_kernel<100, 128, 50, true, 128, 64><<<gemmB, 512, 0, stream>>>(bufB, W2, bufA, N);

    // ---- FUSED layer-2 agg + layer-3 gemv: H2 -> H3 (fp32, stride 8, bufB) ----
    agg_l2f_kernel<50, 64, 6, 8><<<agg_blocks, BT, 0, stream>>>(rowptr, perm, epack, (const uint2*)bufA, dis, b2, W3, bufBf, N);

    // ---- layer 3 aggregation -> out ----
    agg_small_kernel<6, 8><<<agg6_blocks, BT, 0, stream>>>(rowptr, perm, epack, bufBf, dis, b3, out, N);
}